// Round 12
// baseline (714.187 us; speedup 1.0000x reference)
//
#include <hip/hip_runtime.h>
#include <stdint.h>

// Problem constants
#define B_SZ   32
#define N_TOK  1024
#define C_DIM  768
#define HEADS  8
#define CH_DIM 96
#define GM     32768          // B*N rows
#define GN     2304           // 3*C cols
#define GK     768            // K
#define SCALE_F 0.10206207261596577f   // 96^-0.5
#define WHICH_STRIDE 25165824u         // GM*768 elements per q/k/v tensor
#define BH_STRIDE    98304u            // 1024*96

typedef __attribute__((ext_vector_type(8))) short short8;
typedef __attribute__((ext_vector_type(8))) unsigned short ushort8;
typedef __attribute__((ext_vector_type(4))) float f32x4;
typedef __attribute__((ext_vector_type(4))) int int4v;

__device__ __forceinline__ float bf2f(unsigned short u) {
  union { unsigned int i; float f; } x; x.i = ((unsigned int)u) << 16; return x.f;
}
__device__ __forceinline__ unsigned short f2bf(float f) {
  union { float f; unsigned int i; } x; x.f = f;
  unsigned int r = x.i + 0x7fffu + ((x.i >> 16) & 1u);
  return (unsigned short)(r >> 16);
}

// async global->LDS, 16B/lane. LDS dest must be WAVE-UNIFORM; HW adds lane*16.
__device__ __forceinline__ void gload_lds16(const void* g, void* l) {
  __builtin_amdgcn_global_load_lds(
      (const __attribute__((address_space(1))) unsigned int*)g,
      (__attribute__((address_space(3))) unsigned int*)l, 16, 0, 0);
}

// ---------------- fp32 -> int8 per-row dynamic quantization --------------------
__global__ __launch_bounds__(256) void quant_rows(
    const float* __restrict__ x, const float* __restrict__ wq,
    signed char* __restrict__ xq, signed char* __restrict__ wqo,
    float* __restrict__ inv_x, float* __restrict__ inv_w) {
  const int row = blockIdx.x * 4 + (threadIdx.x >> 6);
  const int l = threadIdx.x & 63;
  const float* src; signed char* dst; float* inv; int r;
  if (row < GM) { src = x;  dst = xq;  inv = inv_x; r = row; }
  else { r = row - GM; if (r >= GN) return; src = wq; dst = wqo; inv = inv_w; }

  const float4* s4 = (const float4*)(src + (size_t)r * 768);
  float4 v0 = s4[l], v1 = s4[l + 64], v2 = s4[l + 128];
  float m = fmaxf(fmaxf(fmaxf(fabsf(v0.x), fabsf(v0.y)), fmaxf(fabsf(v0.z), fabsf(v0.w))),
                  fmaxf(fmaxf(fabsf(v1.x), fabsf(v1.y)), fmaxf(fabsf(v1.z), fabsf(v1.w))));
  m = fmaxf(m, fmaxf(fmaxf(fabsf(v2.x), fabsf(v2.y)), fmaxf(fabsf(v2.z), fabsf(v2.w))));
#pragma unroll
  for (int off = 32; off; off >>= 1) m = fmaxf(m, __shfl_xor(m, off));
  const float sc = 127.0f / m;
  if (l == 0) inv[r] = m * (1.0f / 127.0f);

  char4* d4 = (char4*)(dst + (size_t)r * 768);
  char4 o;
  o.x = (signed char)(int)rintf(v0.x * sc); o.y = (signed char)(int)rintf(v0.y * sc);
  o.z = (signed char)(int)rintf(v0.z * sc); o.w = (signed char)(int)rintf(v0.w * sc);
  d4[l] = o;
  o.x = (signed char)(int)rintf(v1.x * sc); o.y = (signed char)(int)rintf(v1.y * sc);
  o.z = (signed char)(int)rintf(v1.z * sc); o.w = (signed char)(int)rintf(v1.w * sc);
  d4[l + 64] = o;
  o.x = (signed char)(int)rintf(v2.x * sc); o.y = (signed char)(int)rintf(v2.y * sc);
  o.z = (signed char)(int)rintf(v2.z * sc); o.w = (signed char)(int)rintf(v2.w * sc);
  d4[l + 128] = o;
}

// ---------------- qkv GEMM, int8 MFMA: 128x256 tile, 2 LDS buffers, 3 blk/CU ---
// 8 waves (2M x 4N), per-wave output 64x64 (acc[4][4] = 64 VGPR). 48 KB LDS and
// VGPR<=80 -> __launch_bounds__(512,6) = 3 blocks/CU (144KB LDS): third block
// covers the vmcnt/barrier drains. Grid 2304 = 768 slots x exactly 3 passes.
// Double-buffer, counted vmcnt(3); swizzle slot ^= (row>>1)&3 (conflict-free).
__global__ __launch_bounds__(512, 6) void qkv_gemm_i8(
    const signed char* __restrict__ xb,   // [GM][768] i8
    const signed char* __restrict__ wb,   // [GN][768] i8 (B^T layout)
    const float* __restrict__ inv_x,      // [GM]
    const float* __restrict__ inv_w,      // [GN]
    unsigned short* __restrict__ qkv) {   // [3][bh][n][96] bf16
  __shared__ __align__(16) char lds[2][24576];   // [buf][A 8KB | B 16KB]

  const int t = threadIdx.x, w = t >> 6, l = t & 63;
  const int l15 = l & 15, lhi = l >> 4;

  // XCD-aware bijective swizzle: nwg = 2304 = 8 * 288
  const int bid = blockIdx.x;
  const int swz = (bid & 7) * 288 + (bid >> 3);
  const int brow = (swz / 9) * 128;
  const int bcol = (swz % 9) * 256;
  const int wr = w >> 2, wc = w & 3;

  const int s_colb = (((l & 3) ^ ((l >> 3) & 3)) << 4);
  const char* gA0 = (const char*)xb + (size_t)brow * 768 + s_colb;
  const char* gB0 = (const char*)wb + (size_t)bcol * 768 + s_colb;

  const int rd_sw = (lhi * 16) ^ (((l15 >> 1) & 3) << 4);
  const int a_off = (wr * 64 + l15) * 64 + rd_sw;          // within A (8 KB)
  const int b_off = 8192 + (wc * 64 + l15) * 64 + rd_sw;   // within B (16 KB)

  int4v acc[4][4];
#pragma unroll
  for (int m = 0; m < 4; ++m)
#pragma unroll
    for (int n = 0; n < 4; ++n) acc[m][n] = (int4v){0, 0, 0, 0};

  auto STAGE = [&](int bi, int kt) {
    const int rowL = w * 16 + (l >> 2);      // 0..127
    gload_lds16(gA0 + (size_t)rowL * 768 + kt * 64,         &lds[bi][w * 1024]);
    gload_lds16(gB0 + (size_t)rowL * 768 + kt * 64,         &lds[bi][8192 + w * 1024]);
    gload_lds16(gB0 + (size_t)(rowL + 128) * 768 + kt * 64, &lds[bi][8192 + (w + 8) * 1024]);
  };

  auto COMPUTE = [&](int bi) {
    int4v af[4], bf8[4];
#pragma unroll
    for (int n = 0; n < 4; ++n)
      bf8[n] = *(const int4v*)(&lds[bi][b_off + n * 1024]);
#pragma unroll
    for (int m = 0; m < 4; ++m)
      af[m] = *(const int4v*)(&lds[bi][a_off + m * 1024]);
    __builtin_amdgcn_s_setprio(1);
#pragma unroll
    for (int m = 0; m < 4; ++m)
#pragma unroll
      for (int n = 0; n < 4; ++n)
        acc[m][n] = __builtin_amdgcn_mfma_i32_16x16x64_i8(af[m], bf8[n], acc[m][n], 0, 0, 0);
    __builtin_amdgcn_s_setprio(0);
  };

#define SB __builtin_amdgcn_sched_barrier(0)
#define BAR do { SB; __builtin_amdgcn_s_barrier(); SB; } while (0)

  STAGE(0, 0); STAGE(1, 1);
  SB; asm volatile("s_waitcnt vmcnt(3)" ::: "memory");  // tile 0 landed
  BAR;

  for (int kt = 0; kt < 12; ++kt) {
    COMPUTE(kt & 1);
    BAR;                                  // all waves done reading buf kt&1
    if (kt < 10) {
      STAGE(kt & 1, kt + 2);              // refill freed buffer
      SB; asm volatile("s_waitcnt vmcnt(3)" ::: "memory");   // tile kt+1 landed
    } else if (kt == 10) {
      SB; asm volatile("s_waitcnt vmcnt(0)" ::: "memory");   // tile 11 landed
    }
    BAR;
  }

  // epilogue: C/D layout col=lane&15, row=(lane>>4)*4+reg (dtype-independent).
  const int bb = brow / 1024;
#pragma unroll
  for (int m = 0; m < 4; ++m) {
    const int row0 = brow + wr * 64 + m * 16 + lhi * 4;
    const int tok0 = row0 & 1023;
    float ix[4];
#pragma unroll
    for (int r = 0; r < 4; ++r) ix[r] = inv_x[row0 + r];
#pragma unroll
    for (int n = 0; n < 4; ++n) {
      const int col   = bcol + wc * 64 + n * 16 + l15;
      const float dq0 = inv_w[col];
      const int which = col / 768;
      const int hh    = (col % 768) / 96;
      const int ch    = col % 96;
      unsigned short* dst = qkv + (size_t)which * WHICH_STRIDE
                          + ((size_t)(bb * 8 + hh)) * BH_STRIDE + ch;
#pragma unroll
      for (int r = 0; r < 4; ++r) {
        float v = (float)acc[m][n][r] * dq0 * ix[r];
        if (which == 1) v = __expf(v);
        dst[(size_t)(tok0 + r) * 96] = f2bf(v);
      }
    }
  }
#undef BAR
#undef SB
}

// ---------------- dd^T = (softmax(k)^T @ v)^T per (b,h) ------------------------
__global__ __launch_bounds__(512, 2) void dd_fused(
    const unsigned short* __restrict__ qkv,
    unsigned short* __restrict__ ddT) {
  __shared__ __align__(16) char smem[124416];
  unsigned short* stg = (unsigned short*)smem;          // [8 waves][2][96*40]
  float* facc = (float*)smem;                           // alias: [2][96][100] fp32
  float* fsum = (float*)(smem + 122880);                // [2][96]
  float* sinv = (float*)(smem + 123648);                // [96]

  const int bh = blockIdx.x;
  const int t = threadIdx.x, w = t >> 6, l = t & 63;
  const int l15 = l & 15, lhi = l >> 4;

  unsigned short* myK = stg + w * 7680;
  unsigned short* myV = myK + 3840;
  const int n   = l >> 1;
  const int chh = l & 1;
  const unsigned short* kb = qkv + WHICH_STRIDE     + (size_t)bh * BH_STRIDE;
  const unsigned short* vb = qkv + 2 * WHICH_STRIDE + (size_t)bh * BH_STRIDE;

  f32x4 acc[6][6], accS[6];
#pragma unroll
  for (int mf = 0; mf < 6; ++mf) {
    accS[mf] = (f32x4){0.f, 0.f, 0.f, 0.f};
#pragma unroll
    for (int nf = 0; nf < 6; ++nf) acc[mf][nf] = (f32x4){0.f, 0.f, 0.f, 0.f};
  }
  short8 ones;
#pragma unroll
  for (int j = 0; j < 8; ++j) ones[j] = (short)0x3F80;   // bf16 1.0

  for (int tt = 0; tt < 4; ++tt) {
    const int n0 = w * 128 + tt * 32;
    const size_t g = (size_t)(n0 + n) * 96 + chh * 48;
#pragma unroll
    for (int i = 0; i < 6; ++i) {
      ushort8 k8 = *(const ushort8*)(kb + g + i * 8);
      ushort8 v8 = *(const ushort8*)(vb + g + i * 8);
      const int c0 = chh * 48 + i * 8;
#pragma unroll
      for (int j = 0; j < 8; ++j) {
        myK[(c0 + j) * 40 + n] = k8[j];
        myV[(c0 + j) * 40 + n] = v8[j];
      }
    }
    short8 af[6], bf8[6];
#pragma unroll
    for (int mf = 0; mf < 6; ++mf)
      af[mf] = *(const short8*)((const char*)myK + (mf * 16 + l15) * 80 + lhi * 16);
#pragma unroll
    for (int nf = 0; nf < 6; ++nf)
      bf8[nf] = *(const short8*)((const char*)myV + (nf * 16 + l15) * 80 + lhi * 16);
#pragma unroll
    for (int mf = 0; mf < 6; ++mf) {
#pragma unroll
      for (int nf = 0; nf < 6; ++nf)
        acc[mf][nf] = __builtin_amdgcn_mfma_f32_16x16x32_bf16(af[mf], bf8[nf], acc[mf][nf], 0, 0, 0);
      accS[mf] = __builtin_amdgcn_mfma_f32_16x16x32_bf16(af[mf], ones, accS[mf], 0, 0, 0);
    }
  }

  __syncthreads();   // staging dead; facc aliases it
  float* fr  = facc + (w >> 2) * 9600;
  float* fsr = fsum + (w >> 2) * 96;
  for (int ww = 0; ww < 4; ++ww) {
    if ((w & 3) == ww) {
#pragma unroll
      for (int mf = 0; mf < 6; ++mf) {
#pragma unroll
        for (int nf = 0; nf < 6; ++nf) {
          const int c = mf * 16 + lhi * 4, d = nf * 16 + l15;
#pragma unroll
          for (int r = 0; r < 4; ++r) {
            float* p = fr + (size_t)(c + r) * 100 + d;
            if (ww == 0) *p = acc[mf][nf][r]; else *p += acc[mf][nf][r];
          }
        }
        if (l15 == 0) {
          const int c = mf * 16 + lhi * 4;
#pragma unroll
          for (int r = 0; r < 4; ++r) {
            if (ww == 0) fsr[c + r] = accS[mf][r];
            else         fsr[c + r] += accS[mf][r];
          }
        }
      }
    }
    __syncthreads();
  }
  for (int i = t; i < 9600; i += 512) facc[i] += facc[9600 + i];
  if (t < 96) fsum[t] += fsum[96 + t];
  __syncthreads();
  if (t < 96) sinv[t] = 1.0f / fsum[t];
  __syncthreads();

  unsigned short* dst = ddT + (size_t)bh * 9216;
#pragma unroll
  for (int e = 0; e < 18; ++e) {
    const int idx = t * 18 + e;
    const int d = idx / 96, c = idx % 96;
    dst[idx] = f2bf(facc[(size_t)c * 100 + d] * sinv[c]);
  }
}

// ---------------- out = SCALE*(q@dd) + q*dwconv3x3(v), rolling v-halo ----------
// grid (2 halves, 8 h, 32 b), 256 thr, 4 waves 2x2 of (32 rows x 48 cols).
// sV = circular buffer of 6 img rows; each iteration stages only 2 NEW rows
// (v fetched from HBM exactly once). Slot for img row y = (y+1)%6; overwritten
// slots were last read 2 iterations ago (loop-end barrier covers).
__global__ __launch_bounds__(256, 2) void factor_conv_p(
    const unsigned short* __restrict__ qkv,
    const unsigned short* __restrict__ ddT,    // [bh][96 d][96 c] bf16
    const float* __restrict__ wcr,             // [768][9]
    const float* __restrict__ bcr,             // [768]
    float* __restrict__ outb) {
  __shared__ __align__(16) unsigned short sQ[64 * 96];      // 12288 B
  __shared__ __align__(16) unsigned short sD[96 * 96];      // 18432 B
  __shared__ __align__(16) unsigned short sV[6 * 32 * 96];  // 36864 B circular
  __shared__ float sW[96 * 9];
  __shared__ float sBias[96];
  const int half = blockIdx.x, h = blockIdx.y, b = blockIdx.z;
  const int t = threadIdx.x, wv = t >> 6, l = t & 63;
  const int l15 = l & 15, lhi = l >> 4;
  const int bh = b * 8 + h;

  // ---- stage ddT + weights once
  const char* dg = (const char*)ddT + (size_t)bh * 18432;
#pragma unroll
  for (int it = 0; it < 4; ++it)
    gload_lds16(dg + (it * 256 + t) * 16, (char*)sD + it * 4096 + wv * 1024);
  if (wv < 2)
    gload_lds16(dg + (1024 + t) * 16, (char*)sD + 16384 + wv * 1024);
  for (int i = t; i < 960; i += 256) {
    if (i < 864) sW[i] = wcr[(size_t)(h * 96) * 9 + i];
    else         sBias[i - 864] = bcr[h * 96 + (i - 864)];
  }

  const char* qg = (const char*)(qkv + (size_t)bh * BH_STRIDE);
  const char* vg = (const char*)(qkv + 2 * WHICH_STRIDE + (size_t)bh * BH_STRIDE);
  const int wrow = (wv >> 1) * 32;
  const int wcol = (wv & 1) * 48;

  // stage img row y (clamped) into circular slot (y+1)%6: 6144 B = 1.5 rounds
  auto STAGE_ROW = [&](int y) {
    const int yy = y < 0 ? 0 : (y > 31 ? 31 : y);
    const int slot = (y + 1) % 6;                      // y >= -1
    const char* src = vg + (size_t)yy * 6144;
    char* dst = (char*)sV + slot * 6144;
    gload_lds16(src + t * 16, dst + wv * 1024);        // bytes 0..4095
    if (wv < 2)
      gload_lds16(src + 4096 + t * 16, dst + 4096 + wv * 1024);  // 4096..6143
  };

  const int Y0 = half * 16;
  STAGE_ROW(Y0 - 1); STAGE_ROW(Y0); STAGE_ROW(Y0 + 1); STAGE_ROW(Y0 + 2);

  for (int it8 = 0; it8 < 8; ++it8) {
    const int Y = Y0 + it8 * 2;
    const int n0 = Y * 32;

    // ---- stage q tile (contiguous 12288 B) + 2 new v rows
#pragma unroll
    for (int it = 0; it < 3; ++it)
      gload_lds16(qg + (size_t)n0 * 192 + (it * 256 + t) * 16,
                  (char*)sQ + it * 4096 + wv * 1024);
    if (it8 > 0) { STAGE_ROW(Y + 1); STAGE_ROW(Y + 2); }
    __syncthreads();   // drains vmcnt

    f32x4 acc[2][3];
#pragma unroll
    for (int m = 0; m < 2; ++m)
#pragma unroll
      for (int nn = 0; nn < 3; ++nn) acc[m][nn] = (f32x4){0.f, 0.f, 0.f, 0.f};

#pragma unroll
    for (int ks = 0; ks < 3; ++ks) {
      short8 af[2], bf8[3];
#pragma unroll
      for (int m = 0; m < 2; ++m)
        af[m] = *(const short8*)((const char*)sQ + (wrow + m*16 + l15) * 192 + ks * 64 + lhi * 16);
#pragma unroll
      for (int nn = 0; nn < 3; ++nn)
        bf8[nn] = *(const short8*)((const char*)sD + (wcol + nn*16 + l15) * 192 + ks * 64 + lhi * 16);
#pragma unroll
      for (int m = 0; m < 2; ++m)
#pragma unroll
        for (int nn = 0; nn < 3; ++nn)
          acc[m][nn] = __builtin_amdgcn_mfma_f32_16x16x32_bf16(af[m], bf8[nn], acc[m][nn], 0, 0, 0);
    }

    // epilogue: conv from circular sV, out = SCALE*acc + q*conv
#pragma unroll
    for (int nn = 0; nn < 3; ++nn) {
      const int dc = wcol + nn * 16 + l15;
      float w9[9];
#pragma unroll
      for (int k = 0; k < 9; ++k) w9[k] = sW[dc * 9 + k];
      const float bv = sBias[dc];
#pragma unroll
      for (int m = 0; m < 2; ++m) {
        const int rl0 = wrow + m * 16 + lhi * 4;     // 4 consecutive rows, same img y
        const int x = rl0 & 31, yl = rl0 >> 5;
        float cs[3][6];
#pragma unroll
        for (int dy = 0; dy < 3; ++dy) {
          const int gy = Y + yl + dy - 1;
          const bool vy = (gy >= 0) && (gy < 32);
          const int slot = (gy + 1) % 6;             // gy >= -1
#pragma unroll
          for (int i = 0; i < 6; ++i) {
            const int xx = x - 1 + i;
            cs[dy][i] = (vy && xx >= 0 && xx < 32)
                ? bf2f(sV[slot * 3072 + xx * 96 + dc]) : 0.f;
          }
        }
#pragma unroll
        for (int r = 0; r < 4; ++r) {
          float conv = bv;
#pragma unroll
          for (int dy = 0; dy < 3; ++dy)
#pragma unroll
            for (int dx = 0; dx < 3; ++dx)
              conv += w9[dy * 3 + dx] * cs[dy][r + dx];
          const int row = rl0 + r;
          const float qv = bf2f(sQ[row * 96 + dc]);
          outb[((size_t)(b * N_TOK + n0 + row)) * C_DIM + h * 96 + dc] =
              SCALE_F * acc[m][nn][r] + qv * conv;
        }
      }
    }
    __syncthreads();   // all sQ/sV readers done before next iter's stage
  }
}

extern "C" void kernel_launch(void* const* d_in, const int* in_sizes, int n_in,
                              void* d_out, int out_size, void* d_ws, size_t ws_size,
                              hipStream_t stream) {
  const float* x      = (const float*)d_in[0];
  const float* w_qkv  = (const float*)d_in[1];
  const float* w_crpe = (const float*)d_in[2];
  const float* b_crpe = (const float*)d_in[3];
  float* out = (float*)d_out;

  char* ws = (char*)d_ws;
  signed char*    xq    = (signed char*)ws;                             // 24 MB i8
  signed char*    wq    = (signed char*)(ws + 25165824);                // 1.7 MB i8
  float*          inv_x = (float*)(ws + 27000832);                      // 128 KB
  float*          inv_w = (float*)(ws + 27131904);                      // 9 KB
  unsigned short* qkv   = (unsigned short*)(ws + 53870592);             // 144 MB, [3][bh][n][96]
  unsigned short* ddT   = (unsigned short*)(ws + 204865536);            // 4.7 MB bf16

  quant_rows<<<dim3((GM + GN + 3) / 4), 256, 0, stream>>>(
      x, w_qkv, xq, wq, inv_x, inv_w);
  qkv_gemm_i8<<<dim3(2304), 512, 0, stream>>>(xq, wq, inv_x, inv_w, qkv);
  dd_fused<<<dim3(B_SZ * HEADS), 512, 0, stream>>>(qkv, ddT);
  factor_conv_p<<<dim3(2, HEADS, B_SZ), 256, 0, stream>>>(qkv, ddT, w_crpe, b_crpe, out);
}

// Round 13
// 207.977 us; speedup vs baseline: 3.4340x; 3.4340x over previous
//
#include <hip/hip_runtime.h>
#include <stdint.h>

// Problem constants
#define B_SZ   32
#define N_TOK  1024
#define C_DIM  768
#define HEADS  8
#define CH_DIM 96
#define GM     32768          // B*N rows
#define GN     2304           // 3*C cols
#define GK     768            // K
#define SCALE_F 0.10206207261596577f   // 96^-0.5
#define WHICH_STRIDE 25165824u         // GM*768 elements per q/k/v tensor
#define BH_STRIDE    98304u            // 1024*96

typedef __attribute__((ext_vector_type(8))) short short8;
typedef __attribute__((ext_vector_type(8))) unsigned short ushort8;
typedef __attribute__((ext_vector_type(4))) float f32x4;
typedef __attribute__((ext_vector_type(4))) int int4v;

__device__ __forceinline__ float bf2f(unsigned short u) {
  union { unsigned int i; float f; } x; x.i = ((unsigned int)u) << 16; return x.f;
}
__device__ __forceinline__ unsigned short f2bf(float f) {
  union { float f; unsigned int i; } x; x.f = f;
  unsigned int r = x.i + 0x7fffu + ((x.i >> 16) & 1u);
  return (unsigned short)(r >> 16);
}

// async global->LDS, 16B/lane. LDS dest must be WAVE-UNIFORM; HW adds lane*16.
__device__ __forceinline__ void gload_lds16(const void* g, void* l) {
  __builtin_amdgcn_global_load_lds(
      (const __attribute__((address_space(1))) unsigned int*)g,
      (__attribute__((address_space(3))) unsigned int*)l, 16, 0, 0);
}

// ---------------- fp32 -> int8 per-row dynamic quantization --------------------
__global__ __launch_bounds__(256) void quant_rows(
    const float* __restrict__ x, const float* __restrict__ wq,
    signed char* __restrict__ xq, signed char* __restrict__ wqo,
    float* __restrict__ inv_x, float* __restrict__ inv_w) {
  const int row = blockIdx.x * 4 + (threadIdx.x >> 6);
  const int l = threadIdx.x & 63;
  const float* src; signed char* dst; float* inv; int r;
  if (row < GM) { src = x;  dst = xq;  inv = inv_x; r = row; }
  else { r = row - GM; if (r >= GN) return; src = wq; dst = wqo; inv = inv_w; }

  const float4* s4 = (const float4*)(src + (size_t)r * 768);
  float4 v0 = s4[l], v1 = s4[l + 64], v2 = s4[l + 128];
  float m = fmaxf(fmaxf(fmaxf(fabsf(v0.x), fabsf(v0.y)), fmaxf(fabsf(v0.z), fabsf(v0.w))),
                  fmaxf(fmaxf(fabsf(v1.x), fabsf(v1.y)), fmaxf(fabsf(v1.z), fabsf(v1.w))));
  m = fmaxf(m, fmaxf(fmaxf(fabsf(v2.x), fabsf(v2.y)), fmaxf(fabsf(v2.z), fabsf(v2.w))));
#pragma unroll
  for (int off = 32; off; off >>= 1) m = fmaxf(m, __shfl_xor(m, off));
  const float sc = 127.0f / m;
  if (l == 0) inv[r] = m * (1.0f / 127.0f);

  char4* d4 = (char4*)(dst + (size_t)r * 768);
  char4 o;
  o.x = (signed char)(int)rintf(v0.x * sc); o.y = (signed char)(int)rintf(v0.y * sc);
  o.z = (signed char)(int)rintf(v0.z * sc); o.w = (signed char)(int)rintf(v0.w * sc);
  d4[l] = o;
  o.x = (signed char)(int)rintf(v1.x * sc); o.y = (signed char)(int)rintf(v1.y * sc);
  o.z = (signed char)(int)rintf(v1.z * sc); o.w = (signed char)(int)rintf(v1.w * sc);
  d4[l + 64] = o;
  o.x = (signed char)(int)rintf(v2.x * sc); o.y = (signed char)(int)rintf(v2.y * sc);
  o.z = (signed char)(int)rintf(v2.z * sc); o.w = (signed char)(int)rintf(v2.w * sc);
  d4[l + 128] = o;
}

// ---------------- qkv GEMM, int8 MFMA: 128x256 tile, 3 LDS buffers, 2 blk/CU ---
// 8 waves (2M x 4N), per-wave output 64x64. __launch_bounds__(512,4) — the
// PROVEN no-spill config (round 12's (512,6) caused a 40-VGPR spill disaster).
// 3 buffers x 24KB = 72KB -> still 2 blocks/CU; prefetch TWO tiles ahead with
// counted vmcnt(6): the tile-(kt+1) wait has ~2 compute-tiles of slack, fully
// hiding ~900cy HBM latency. Swizzle slot ^= (row>>1)&3 (conflict-free).
__global__ __launch_bounds__(512, 4) void qkv_gemm_i8(
    const signed char* __restrict__ xb,   // [GM][768] i8
    const signed char* __restrict__ wb,   // [GN][768] i8 (B^T layout)
    const float* __restrict__ inv_x,      // [GM]
    const float* __restrict__ inv_w,      // [GN]
    unsigned short* __restrict__ qkv) {   // [3][bh][n][96] bf16
  __shared__ __align__(16) char lds[3][24576];   // [buf][A 8KB | B 16KB]

  const int t = threadIdx.x, w = t >> 6, l = t & 63;
  const int l15 = l & 15, lhi = l >> 4;

  // XCD-aware bijective swizzle: nwg = 2304 = 8 * 288
  const int bid = blockIdx.x;
  const int swz = (bid & 7) * 288 + (bid >> 3);
  const int brow = (swz / 9) * 128;
  const int bcol = (swz % 9) * 256;
  const int wr = w >> 2, wc = w & 3;

  const int s_colb = (((l & 3) ^ ((l >> 3) & 3)) << 4);
  const char* gA0 = (const char*)xb + (size_t)brow * 768 + s_colb;
  const char* gB0 = (const char*)wb + (size_t)bcol * 768 + s_colb;

  const int rd_sw = (lhi * 16) ^ (((l15 >> 1) & 3) << 4);
  const int a_off = (wr * 64 + l15) * 64 + rd_sw;          // within A (8 KB)
  const int b_off = 8192 + (wc * 64 + l15) * 64 + rd_sw;   // within B (16 KB)

  int4v acc[4][4];
#pragma unroll
  for (int m = 0; m < 4; ++m)
#pragma unroll
    for (int n = 0; n < 4; ++n) acc[m][n] = (int4v){0, 0, 0, 0};

  auto STAGE = [&](int bi, int kt) {
    const int rowL = w * 16 + (l >> 2);      // 0..127
    gload_lds16(gA0 + (size_t)rowL * 768 + kt * 64,         &lds[bi][w * 1024]);
    gload_lds16(gB0 + (size_t)rowL * 768 + kt * 64,         &lds[bi][8192 + w * 1024]);
    gload_lds16(gB0 + (size_t)(rowL + 128) * 768 + kt * 64, &lds[bi][8192 + (w + 8) * 1024]);
  };

  auto COMPUTE = [&](int bi) {
    int4v af[4], bf8[4];
#pragma unroll
    for (int n = 0; n < 4; ++n)
      bf8[n] = *(const int4v*)(&lds[bi][b_off + n * 1024]);
#pragma unroll
    for (int m = 0; m < 4; ++m)
      af[m] = *(const int4v*)(&lds[bi][a_off + m * 1024]);
    __builtin_amdgcn_s_setprio(1);
#pragma unroll
    for (int m = 0; m < 4; ++m)
#pragma unroll
      for (int n = 0; n < 4; ++n)
        acc[m][n] = __builtin_amdgcn_mfma_i32_16x16x64_i8(af[m], bf8[n], acc[m][n], 0, 0, 0);
    __builtin_amdgcn_s_setprio(0);
  };

#define SB __builtin_amdgcn_sched_barrier(0)
#define BAR do { SB; __builtin_amdgcn_s_barrier(); SB; } while (0)

  // prologue: 3 K-tiles in flight (9 loads/thread); wait tile 0 only.
  STAGE(0, 0); STAGE(1, 1); STAGE(2, 2);
  SB; asm volatile("s_waitcnt vmcnt(6)" ::: "memory");
  BAR;

#pragma unroll
  for (int kt = 0; kt < 12; ++kt) {
    COMPUTE(kt % 3);
    BAR;                                  // all waves done reading buf kt%3
    if (kt < 9) {
      STAGE(kt % 3, kt + 3);              // refill freed buffer, 2 tiles ahead
      SB; asm volatile("s_waitcnt vmcnt(6)" ::: "memory");   // tile kt+1 landed
    } else if (kt == 9) {
      SB; asm volatile("s_waitcnt vmcnt(3)" ::: "memory");   // tile 10 landed
    } else if (kt == 10) {
      SB; asm volatile("s_waitcnt vmcnt(0)" ::: "memory");   // tile 11 landed
    }
    BAR;
  }

  // epilogue: C/D layout col=lane&15, row=(lane>>4)*4+reg (dtype-independent).
  const int bb = brow / 1024;
#pragma unroll
  for (int m = 0; m < 4; ++m) {
    const int row0 = brow + wr * 64 + m * 16 + lhi * 4;
    const int tok0 = row0 & 1023;
    float ix[4];
#pragma unroll
    for (int r = 0; r < 4; ++r) ix[r] = inv_x[row0 + r];
#pragma unroll
    for (int n = 0; n < 4; ++n) {
      const int col   = bcol + wc * 64 + n * 16 + l15;
      const float dq0 = inv_w[col];
      const int which = col / 768;
      const int hh    = (col % 768) / 96;
      const int ch    = col % 96;
      unsigned short* dst = qkv + (size_t)which * WHICH_STRIDE
                          + ((size_t)(bb * 8 + hh)) * BH_STRIDE + ch;
#pragma unroll
      for (int r = 0; r < 4; ++r) {
        float v = (float)acc[m][n][r] * dq0 * ix[r];
        if (which == 1) v = __expf(v);
        dst[(size_t)(tok0 + r) * 96] = f2bf(v);
      }
    }
  }
#undef BAR
#undef SB
}

// ---------------- dd^T = (softmax(k)^T @ v)^T per (b,h) ------------------------
__global__ __launch_bounds__(512, 2) void dd_fused(
    const unsigned short* __restrict__ qkv,
    unsigned short* __restrict__ ddT) {
  __shared__ __align__(16) char smem[124416];
  unsigned short* stg = (unsigned short*)smem;          // [8 waves][2][96*40]
  float* facc = (float*)smem;                           // alias: [2][96][100] fp32
  float* fsum = (float*)(smem + 122880);                // [2][96]
  float* sinv = (float*)(smem + 123648);                // [96]

  const int bh = blockIdx.x;
  const int t = threadIdx.x, w = t >> 6, l = t & 63;
  const int l15 = l & 15, lhi = l >> 4;

  unsigned short* myK = stg + w * 7680;
  unsigned short* myV = myK + 3840;
  const int n   = l >> 1;
  const int chh = l & 1;
  const unsigned short* kb = qkv + WHICH_STRIDE     + (size_t)bh * BH_STRIDE;
  const unsigned short* vb = qkv + 2 * WHICH_STRIDE + (size_t)bh * BH_STRIDE;

  f32x4 acc[6][6], accS[6];
#pragma unroll
  for (int mf = 0; mf < 6; ++mf) {
    accS[mf] = (f32x4){0.f, 0.f, 0.f, 0.f};
#pragma unroll
    for (int nf = 0; nf < 6; ++nf) acc[mf][nf] = (f32x4){0.f, 0.f, 0.f, 0.f};
  }
  short8 ones;
#pragma unroll
  for (int j = 0; j < 8; ++j) ones[j] = (short)0x3F80;   // bf16 1.0

  for (int tt = 0; tt < 4; ++tt) {
    const int n0 = w * 128 + tt * 32;
    const size_t g = (size_t)(n0 + n) * 96 + chh * 48;
#pragma unroll
    for (int i = 0; i < 6; ++i) {
      ushort8 k8 = *(const ushort8*)(kb + g + i * 8);
      ushort8 v8 = *(const ushort8*)(vb + g + i * 8);
      const int c0 = chh * 48 + i * 8;
#pragma unroll
      for (int j = 0; j < 8; ++j) {
        myK[(c0 + j) * 40 + n] = k8[j];
        myV[(c0 + j) * 40 + n] = v8[j];
      }
    }
    short8 af[6], bf8[6];
#pragma unroll
    for (int mf = 0; mf < 6; ++mf)
      af[mf] = *(const short8*)((const char*)myK + (mf * 16 + l15) * 80 + lhi * 16);
#pragma unroll
    for (int nf = 0; nf < 6; ++nf)
      bf8[nf] = *(const short8*)((const char*)myV + (nf * 16 + l15) * 80 + lhi * 16);
#pragma unroll
    for (int mf = 0; mf < 6; ++mf) {
#pragma unroll
      for (int nf = 0; nf < 6; ++nf)
        acc[mf][nf] = __builtin_amdgcn_mfma_f32_16x16x32_bf16(af[mf], bf8[nf], acc[mf][nf], 0, 0, 0);
      accS[mf] = __builtin_amdgcn_mfma_f32_16x16x32_bf16(af[mf], ones, accS[mf], 0, 0, 0);
    }
  }

  __syncthreads();   // staging dead; facc aliases it
  float* fr  = facc + (w >> 2) * 9600;
  float* fsr = fsum + (w >> 2) * 96;
  for (int ww = 0; ww < 4; ++ww) {
    if ((w & 3) == ww) {
#pragma unroll
      for (int mf = 0; mf < 6; ++mf) {
#pragma unroll
        for (int nf = 0; nf < 6; ++nf) {
          const int c = mf * 16 + lhi * 4, d = nf * 16 + l15;
#pragma unroll
          for (int r = 0; r < 4; ++r) {
            float* p = fr + (size_t)(c + r) * 100 + d;
            if (ww == 0) *p = acc[mf][nf][r]; else *p += acc[mf][nf][r];
          }
        }
        if (l15 == 0) {
          const int c = mf * 16 + lhi * 4;
#pragma unroll
          for (int r = 0; r < 4; ++r) {
            if (ww == 0) fsr[c + r] = accS[mf][r];
            else         fsr[c + r] += accS[mf][r];
          }
        }
      }
    }
    __syncthreads();
  }
  for (int i = t; i < 9600; i += 512) facc[i] += facc[9600 + i];
  if (t < 96) fsum[t] += fsum[96 + t];
  __syncthreads();
  if (t < 96) sinv[t] = 1.0f / fsum[t];
  __syncthreads();

  unsigned short* dst = ddT + (size_t)bh * 9216;
#pragma unroll
  for (int e = 0; e < 18; ++e) {
    const int idx = t * 18 + e;
    const int d = idx / 96, c = idx % 96;
    dst[idx] = f2bf(facc[(size_t)c * 100 + d] * sinv[c]);
  }
}

// ---------------- out = SCALE*(q@dd) + q*dwconv3x3(v), rolling v-halo ----------
__global__ __launch_bounds__(256, 2) void factor_conv_p(
    const unsigned short* __restrict__ qkv,
    const unsigned short* __restrict__ ddT,    // [bh][96 d][96 c] bf16
    const float* __restrict__ wcr,             // [768][9]
    const float* __restrict__ bcr,             // [768]
    float* __restrict__ outb) {
  __shared__ __align__(16) unsigned short sQ[64 * 96];      // 12288 B
  __shared__ __align__(16) unsigned short sD[96 * 96];      // 18432 B
  __shared__ __align__(16) unsigned short sV[6 * 32 * 96];  // 36864 B circular
  __shared__ float sW[96 * 9];
  __shared__ float sBias[96];
  const int half = blockIdx.x, h = blockIdx.y, b = blockIdx.z;
  const int t = threadIdx.x, wv = t >> 6, l = t & 63;
  const int l15 = l & 15, lhi = l >> 4;
  const int bh = b * 8 + h;

  const char* dg = (const char*)ddT + (size_t)bh * 18432;
#pragma unroll
  for (int it = 0; it < 4; ++it)
    gload_lds16(dg + (it * 256 + t) * 16, (char*)sD + it * 4096 + wv * 1024);
  if (wv < 2)
    gload_lds16(dg + (1024 + t) * 16, (char*)sD + 16384 + wv * 1024);
  for (int i = t; i < 960; i += 256) {
    if (i < 864) sW[i] = wcr[(size_t)(h * 96) * 9 + i];
    else         sBias[i - 864] = bcr[h * 96 + (i - 864)];
  }

  const char* qg = (const char*)(qkv + (size_t)bh * BH_STRIDE);
  const char* vg = (const char*)(qkv + 2 * WHICH_STRIDE + (size_t)bh * BH_STRIDE);
  const int wrow = (wv >> 1) * 32;
  const int wcol = (wv & 1) * 48;

  auto STAGE_ROW = [&](int y) {
    const int yy = y < 0 ? 0 : (y > 31 ? 31 : y);
    const int slot = (y + 1) % 6;                      // y >= -1
    const char* src = vg + (size_t)yy * 6144;
    char* dst = (char*)sV + slot * 6144;
    gload_lds16(src + t * 16, dst + wv * 1024);
    if (wv < 2)
      gload_lds16(src + 4096 + t * 16, dst + 4096 + wv * 1024);
  };

  const int Y0 = half * 16;
  STAGE_ROW(Y0 - 1); STAGE_ROW(Y0); STAGE_ROW(Y0 + 1); STAGE_ROW(Y0 + 2);

  for (int it8 = 0; it8 < 8; ++it8) {
    const int Y = Y0 + it8 * 2;
    const int n0 = Y * 32;

#pragma unroll
    for (int it = 0; it < 3; ++it)
      gload_lds16(qg + (size_t)n0 * 192 + (it * 256 + t) * 16,
                  (char*)sQ + it * 4096 + wv * 1024);
    if (it8 > 0) { STAGE_ROW(Y + 1); STAGE_ROW(Y + 2); }
    __syncthreads();   // drains vmcnt

    f32x4 acc[2][3];
#pragma unroll
    for (int m = 0; m < 2; ++m)
#pragma unroll
      for (int nn = 0; nn < 3; ++nn) acc[m][nn] = (f32x4){0.f, 0.f, 0.f, 0.f};

#pragma unroll
    for (int ks = 0; ks < 3; ++ks) {
      short8 af[2], bf8[3];
#pragma unroll
      for (int m = 0; m < 2; ++m)
        af[m] = *(const short8*)((const char*)sQ + (wrow + m*16 + l15) * 192 + ks * 64 + lhi * 16);
#pragma unroll
      for (int nn = 0; nn < 3; ++nn)
        bf8[nn] = *(const short8*)((const char*)sD + (wcol + nn*16 + l15) * 192 + ks * 64 + lhi * 16);
#pragma unroll
      for (int m = 0; m < 2; ++m)
#pragma unroll
        for (int nn = 0; nn < 3; ++nn)
          acc[m][nn] = __builtin_amdgcn_mfma_f32_16x16x32_bf16(af[m], bf8[nn], acc[m][nn], 0, 0, 0);
    }

#pragma unroll
    for (int nn = 0; nn < 3; ++nn) {
      const int dc = wcol + nn * 16 + l15;
      float w9[9];
#pragma unroll
      for (int k = 0; k < 9; ++k) w9[k] = sW[dc * 9 + k];
      const float bv = sBias[dc];
#pragma unroll
      for (int m = 0; m < 2; ++m) {
        const int rl0 = wrow + m * 16 + lhi * 4;
        const int x = rl0 & 31, yl = rl0 >> 5;
        float cs[3][6];
#pragma unroll
        for (int dy = 0; dy < 3; ++dy) {
          const int gy = Y + yl + dy - 1;
          const bool vy = (gy >= 0) && (gy < 32);
          const int slot = (gy + 1) % 6;
#pragma unroll
          for (int i = 0; i < 6; ++i) {
            const int xx = x - 1 + i;
            cs[dy][i] = (vy && xx >= 0 && xx < 32)
                ? bf2f(sV[slot * 3072 + xx * 96 + dc]) : 0.f;
          }
        }
#pragma unroll
        for (int r = 0; r < 4; ++r) {
          float conv = bv;
#pragma unroll
          for (int dy = 0; dy < 3; ++dy)
#pragma unroll
            for (int dx = 0; dx < 3; ++dx)
              conv += w9[dy * 3 + dx] * cs[dy][r + dx];
          const int row = rl0 + r;
          const float qv = bf2f(sQ[row * 96 + dc]);
          outb[((size_t)(b * N_TOK + n0 + row)) * C_DIM + h * 96 + dc] =
              SCALE_F * acc[m][nn][r] + qv * conv;
        }
      }
    }
    __syncthreads();
  }
}

extern "C" void kernel_launch(void* const* d_in, const int* in_sizes, int n_in,
                              void* d_out, int out_size, void* d_ws, size_t ws_size,
                              hipStream_t stream) {
  const float* x      = (const float*)d_in[0];
  const float* w_qkv  = (const float*)d_in[1];
  const float* w_crpe = (const float*)d_in[2];
  const float* b_crpe = (const float*)d_in[3];
  float* out = (float*)d_out;

  char* ws = (char*)d_ws;
  signed char*    xq    = (signed char*)ws;                             // 24 MB i8
  signed char*    wq    = (signed char*)(ws + 25165824);                // 1.7 MB i8
  float*          inv_x = (float*)(ws + 27000832);                      // 128 KB
  float*          inv_w = (float*)(ws + 27131904);                      // 9 KB
  unsigned short* qkv   = (unsigned short*)(ws + 53870592);             // 144 MB, [3][bh][n][96]
  unsigned short* ddT   = (unsigned short*)(ws + 204865536);            // 4.7 MB bf16

  quant_rows<<<dim3((GM + GN + 3) / 4), 256, 0, stream>>>(
      x, w_qkv, xq, wq, inv_x, inv_w);
  qkv_gemm_i8<<<dim3(2304), 512, 0, stream>>>(xq, wq, inv_x, inv_w, qkv);
  dd_fused<<<dim3(B_SZ * HEADS), 512, 0, stream>>>(qkv, ddT);
  factor_conv_p<<<dim3(2, HEADS, B_SZ), 256, 0, stream>>>(qkv, ddT, w_crpe, b_crpe, out);
}